// Round 5
// baseline (279.582 us; speedup 1.0000x reference)
//
#include <hip/hip_runtime.h>

// Fused attention block for MI355X (gfx950).
// x[4096,768] fp32 -> QKV bf16 GEMM -> flash attention (12 heads, D=64) -> proj GEMM -> fp32 out.
// flash_attn v3: 32x32x16 MFMA, wave-private 64-key chunks, K/V global->VGPR (no LDS in the
// K loop, no barriers), P via lane^32 register exchange, per-wave O reduced through LDS once.
// Layouts (16x16 verified on HW rounds 1-4; 32x32 follows the same lane pattern):
//   A: m=lane&31, k=(lane>>5)*8+j ; B: n=lane&31, k=(lane>>5)*8+j ;
//   C/D (HW-verified m74/m101): col=lane&31, row=(reg&3)+8*(reg>>2)+4*(lane>>5).

typedef short bf16x8 __attribute__((ext_vector_type(8)));
typedef float f32x4 __attribute__((ext_vector_type(4)));
typedef float f32x16 __attribute__((ext_vector_type(16)));
typedef unsigned short u16;
typedef unsigned int u32;

__device__ __forceinline__ u16 f2bf(float f) {
  u32 u = __float_as_uint(f);
  u = (u + 0x7fffu + ((u >> 16) & 1u)) >> 16;  // RNE
  return (u16)u;
}

// pack two fp32 -> bf16 pair [a low, b high], RNE
__device__ __forceinline__ u32 packbf(float a, float b) {
  u32 ua = __float_as_uint(a), ub = __float_as_uint(b);
  ua += 0x7fffu + ((ua >> 16) & 1u);
  ub += 0x7fffu + ((ub >> 16) & 1u);
  return __builtin_amdgcn_perm(ub, ua, 0x07060302);
}

// cheap pack: round-half-up (0.5 ulp max, 3 ops) — used in the hot loop
__device__ __forceinline__ u32 packbf_hu(float a, float b) {
  return __builtin_amdgcn_perm(__float_as_uint(b) + 0x8000u,
                               __float_as_uint(a) + 0x8000u, 0x07060302);
}

__device__ __forceinline__ void gload16(const void* g, void* l) {
  __builtin_amdgcn_global_load_lds(
      (const __attribute__((address_space(1))) unsigned int*)g,
      (__attribute__((address_space(3))) unsigned int*)l, 16, 0, 0);
}

// ---------------- fused fp32 -> bf16 cast of x, qkv_w, proj_w ----------------
__global__ void cast3(const float* __restrict__ a, int na4,
                      const float* __restrict__ b, int nb4,
                      const float* __restrict__ c, int nc4,
                      u16* __restrict__ oa, u16* __restrict__ obp, u16* __restrict__ oc) {
  int i = blockIdx.x * blockDim.x + threadIdx.x;
  const float* src;
  u16* dst;
  int j = i;
  if (i < na4) { src = a; dst = oa; }
  else if (i < na4 + nb4) { src = b; dst = obp; j = i - na4; }
  else if (i < na4 + nb4 + nc4) { src = c; dst = oc; j = i - na4 - nb4; }
  else return;
  float4 v = ((const float4*)src)[j];
  ushort4 o;
  o.x = f2bf(v.x); o.y = f2bf(v.y); o.z = f2bf(v.z); o.w = f2bf(v.w);
  ((ushort4*)dst)[j] = o;
}

// ---------------- m97-style GEMM: C[M,N] = A[M,K] * B[N,K]^T + bias ----------------
// MODE 0: scatter bf16 into q/k/v. q,k: [H][4096][64] (q pre-scaled by 8*log2e); v: [H][64][4096].
// MODE 1: fp32 out[M,N] (final projection, N=768)
template <int MODE>
__global__ __launch_bounds__(256, 2) void gemm_bt(
    const u16* __restrict__ A, const u16* __restrict__ B,
    const float* __restrict__ bias,
    u16* __restrict__ qb, u16* __restrict__ kbuf, u16* __restrict__ vb,
    float* __restrict__ outp, int K, int N) {
  __shared__ __align__(16) u16 As[128 * 32];
  __shared__ __align__(16) u16 Bs[128 * 32];
  const int tid = threadIdx.x, lane = tid & 63, w = tid >> 6;
  const int wr = w >> 1, wc = w & 1, quad = lane >> 4, l15 = lane & 15;
  const int m0 = blockIdx.y * 128, n0 = blockIdx.x * 128;

  f32x4 acc[4][4];
#pragma unroll
  for (int i = 0; i < 4; ++i)
#pragma unroll
    for (int j = 0; j < 4; ++j) acc[i][j] = (f32x4){0.f, 0.f, 0.f, 0.f};

  for (int k0 = 0; k0 < K; k0 += 32) {
    __syncthreads();
#pragma unroll
    for (int i = 0; i < 2; ++i) {
      int chunk = i * 256 + w * 64 + lane;
      int row = chunk >> 2, kc = chunk & 3;
      gload16(A + (size_t)(m0 + row) * K + k0 + kc * 8, (char*)As + chunk * 16);
      gload16(B + (size_t)(n0 + row) * K + k0 + kc * 8, (char*)Bs + chunk * 16);
    }
    __syncthreads();
    bf16x8 af[4], bfr[4];
#pragma unroll
    for (int mi = 0; mi < 4; ++mi)
      af[mi] = *(const bf16x8*)&As[(wr * 64 + mi * 16 + l15) * 32 + quad * 8];
#pragma unroll
    for (int ni = 0; ni < 4; ++ni)
      bfr[ni] = *(const bf16x8*)&Bs[(wc * 64 + ni * 16 + l15) * 32 + quad * 8];
#pragma unroll
    for (int mi = 0; mi < 4; ++mi)
#pragma unroll
      for (int ni = 0; ni < 4; ++ni)
        acc[mi][ni] = __builtin_amdgcn_mfma_f32_16x16x32_bf16(af[mi], bfr[ni], acc[mi][ni], 0, 0, 0);
  }

#pragma unroll
  for (int mi = 0; mi < 4; ++mi) {
    int row = m0 + wr * 64 + mi * 16 + quad * 4;
#pragma unroll
    for (int ni = 0; ni < 4; ++ni) {
      int col = n0 + wc * 64 + ni * 16 + l15;
      float bv = bias[col];
      if (MODE == 0) {
        int t = col / 768;
        int rem = col - t * 768;
        int hh = rem >> 6, d = rem & 63;
        if (t == 2) {
          u16* dst = vb + (size_t)hh * 64 * 4096 + (size_t)d * 4096 + row;
          ushort4 pk;
          pk.x = f2bf(acc[mi][ni][0] + bv);
          pk.y = f2bf(acc[mi][ni][1] + bv);
          pk.z = f2bf(acc[mi][ni][2] + bv);
          pk.w = f2bf(acc[mi][ni][3] + bv);
          *(ushort4*)dst = pk;
        } else {
          u16* dst = (t == 0 ? qb : kbuf) + (size_t)hh * 4096 * 64 + d;
          float sc = (t == 0) ? 11.541560327111707f : 1.f;  // 8*log2(e)
#pragma unroll
          for (int r = 0; r < 4; ++r)
            dst[(size_t)(row + r) * 64] = f2bf((acc[mi][ni][r] + bv) * sc);
        }
      } else {
#pragma unroll
        for (int r = 0; r < 4; ++r)
          outp[(size_t)(row + r) * N + col] = acc[mi][ni][r] + bv;
      }
    }
  }
}

// ---------------- flash attention v3: LDS-free K loop ----------------
// block = (64 q-rows, head), 4 waves; wave w owns keys {t*256 + w*64 .. +63}.
__global__ __launch_bounds__(256, 2) void flash_attn(
    const u16* __restrict__ qb, const u16* __restrict__ kb,
    const u16* __restrict__ vtg, u16* __restrict__ ob) {
  __shared__ float osh[4][64][64];   // per-wave partial O
  __shared__ float lssh[4][2][64];   // per-wave, per-half lsum[q]
  const int b = blockIdx.x;
  const int gg = (b & 7) * 96 + (b >> 3);   // XCD swizzle: 1.5 heads per XCD
  const int h = gg >> 6;
  const int q0 = (gg & 63) * 64;

  const int tid = threadIdx.x, lane = tid & 63, w = tid >> 6;
  const int col = lane & 31, g = lane >> 5;
  const u16* qh = qb + (size_t)h * 4096 * 64;
  const u16* kh = kb + (size_t)h * 4096 * 64;
  const u16* vh = vtg + (size_t)h * 64 * 4096;  // [d][key]

  // Q B-frags (loop-invariant): n = q0 + nt*32 + col, k(d) = kd*16 + g*8 + j
  bf16x8 qf[2][4];
#pragma unroll
  for (int nt = 0; nt < 2; ++nt)
#pragma unroll
    for (int kd = 0; kd < 4; ++kd)
      qf[nt][kd] = *(const bf16x8*)&qh[(size_t)(q0 + nt * 32 + col) * 64 + kd * 16 + g * 8];

  f32x16 oacc[2][2];  // [q-tile][d-tile]
#pragma unroll
  for (int i = 0; i < 2; ++i)
#pragma unroll
    for (int j = 0; j < 2; ++j)
#pragma unroll
      for (int r = 0; r < 16; ++r) oacc[i][j][r] = 0.f;
  float ls0 = 0.f, ls1 = 0.f;  // lsum for q=col and q=col+32

  // K A-frag pointers: row = kt + mt*32 + col, off = kd*16 + g*8
  const u16* kwp = kh + (size_t)(w * 64 + col) * 64 + g * 8;
  bf16x8 kc[2][4];
#pragma unroll
  for (int mt = 0; mt < 2; ++mt)
#pragma unroll
    for (int kd = 0; kd < 4; ++kd)
      kc[mt][kd] = *(const bf16x8*)(kwp + mt * 2048 + kd * 16);

#pragma unroll 2
  for (int t = 0; t < 16; ++t) {
    const size_t kt = (size_t)t * 256 + w * 64;

    // V B-frags for this chunk (issued early; consumed after the exp phase)
    bf16x8 vf[2][4];
#pragma unroll
    for (int nt = 0; nt < 2; ++nt)
#pragma unroll
      for (int ks = 0; ks < 4; ++ks)
        vf[nt][ks] = *(const bf16x8*)&vh[(size_t)(nt * 32 + col) * 4096 + kt + ks * 16 + g * 8];

    // S^T = K*Q^T per 32-key m-tile; exp+pack immediately to limit register liveness
    u32 pd[2][2][8];  // [mt][q-tile][dword] packed bf16 P pairs
#pragma unroll
    for (int mt = 0; mt < 2; ++mt) {
      f32x16 s[2];
#pragma unroll
      for (int mo = 0; mo < 2; ++mo)
#pragma unroll
        for (int r = 0; r < 16; ++r) s[mo][r] = 0.f;
#pragma unroll
      for (int kd = 0; kd < 4; ++kd) {
        s[0] = __builtin_amdgcn_mfma_f32_32x32x16_bf16(kc[mt][kd], qf[0][kd], s[0], 0, 0, 0);
        s[1] = __builtin_amdgcn_mfma_f32_32x32x16_bf16(kc[mt][kd], qf[1][kd], s[1], 0, 0, 0);
      }
      // prefetch next chunk's K frags for this mt (full compute-phase of latency cover)
      if (t < 15) {
        const u16* knp = kwp + (size_t)(t + 1) * 16384 + mt * 2048;
#pragma unroll
        for (int kd = 0; kd < 4; ++kd)
          kc[mt][kd] = *(const bf16x8*)(knp + kd * 16);
      }
#pragma unroll
      for (int mo = 0; mo < 2; ++mo)
#pragma unroll
        for (int j = 0; j < 8; ++j) {
          float pa = exp2f(s[mo][2 * j]);
          float pb = exp2f(s[mo][2 * j + 1]);
          if (mo == 0) ls0 += pa + pb; else ls1 += pa + pb;
          pd[mt][mo][j] = packbf_hu(pa, pb);
        }
    }

    // PV: A = P built by lane^32 exchange, B = V^T frags
#pragma unroll
    for (int mo = 0; mo < 2; ++mo)
#pragma unroll
      for (int ks = 0; ks < 4; ++ks) {
        const u32* arr = pd[ks >> 1][mo];
        const int i0 = (ks & 1) * 4;
        u32 a0 = arr[i0], a1 = arr[i0 + 1], a2 = arr[i0 + 2], a3 = arr[i0 + 3];
        u32 s1 = (u32)__shfl_xor((int)(g ? a0 : a2), 32);
        u32 s2 = (u32)__shfl_xor((int)(g ? a1 : a3), 32);
        uint4 ad;
        ad.x = g ? s1 : a0;
        ad.y = g ? s2 : a1;
        ad.z = g ? a2 : s1;
        ad.w = g ? a3 : s2;
        bf16x8 pf = __builtin_bit_cast(bf16x8, ad);
        oacc[mo][0] = __builtin_amdgcn_mfma_f32_32x32x16_bf16(pf, vf[0][ks], oacc[mo][0], 0, 0, 0);
        oacc[mo][1] = __builtin_amdgcn_mfma_f32_32x32x16_bf16(pf, vf[1][ks], oacc[mo][1], 0, 0, 0);
      }
  }

  // ---- cross-wave reduction ----
#pragma unroll
  for (int mo = 0; mo < 2; ++mo)
#pragma unroll
    for (int nt = 0; nt < 2; ++nt)
#pragma unroll
      for (int r = 0; r < 16; ++r) {
        int q = mo * 32 + (r & 3) + 8 * (r >> 2) + 4 * g;
        osh[w][q][nt * 32 + col] = oacc[mo][nt][r];
      }
  lssh[w][g][col] = ls0;
  lssh[w][g][col + 32] = ls1;
  __syncthreads();

  // wave w reduces q-rows [w*16, w*16+16); 4 lanes per row, 16 d each
  const int qr = w * 16 + (lane >> 2);
  const int d0 = (lane & 3) * 16;
  float acc[16];
#pragma unroll
  for (int i = 0; i < 16; ++i) acc[i] = 0.f;
#pragma unroll
  for (int ww = 0; ww < 4; ++ww)
#pragma unroll
    for (int j = 0; j < 4; ++j) {
      float4 v = *(const float4*)&osh[ww][qr][d0 + j * 4];
      acc[4 * j + 0] += v.x; acc[4 * j + 1] += v.y;
      acc[4 * j + 2] += v.z; acc[4 * j + 3] += v.w;
    }
  float ls = 0.f;
#pragma unroll
  for (int ww = 0; ww < 4; ++ww) ls += lssh[ww][0][qr] + lssh[ww][1][qr];
  float linv = 1.f / ls;
  u32 ow[8];
#pragma unroll
  for (int j = 0; j < 8; ++j)
    ow[j] = packbf(acc[2 * j] * linv, acc[2 * j + 1] * linv);
  u16* op = ob + (size_t)(q0 + qr) * 768 + h * 64 + d0;
  *(uint4*)op = make_uint4(ow[0], ow[1], ow[2], ow[3]);
  *(uint4*)(op + 8) = make_uint4(ow[4], ow[5], ow[6], ow[7]);
}

extern "C" void kernel_launch(void* const* d_in, const int* in_sizes, int n_in,
                              void* d_out, int out_size, void* d_ws, size_t ws_size,
                              hipStream_t stream) {
  const float* x      = (const float*)d_in[0];
  const float* qkv_w  = (const float*)d_in[1];
  const float* qkv_b  = (const float*)d_in[2];
  const float* proj_w = (const float*)d_in[3];
  const float* proj_b = (const float*)d_in[4];
  float* out = (float*)d_out;

  const int N = 4096, C = 768, H = 12, D = 64, C3 = 2304;
  char* ws = (char*)d_ws;
  size_t off = 0;
  u16* xb    = (u16*)(ws + off); off += (size_t)N * C * 2;
  u16* wqkv  = (u16*)(ws + off); off += (size_t)C3 * C * 2;
  u16* wproj = (u16*)(ws + off); off += (size_t)C * C * 2;
  u16* qbuf  = (u16*)(ws + off); off += (size_t)H * N * D * 2;
  u16* kbuf  = (u16*)(ws + off); off += (size_t)H * N * D * 2;
  u16* vbuf  = (u16*)(ws + off); off += (size_t)H * N * D * 2;  // V^T [H][64][4096]
  u16* aob = xb;  // xb dead after QKV GEMM

  const int na4 = N * C / 4, nb4 = C3 * C / 4, nc4 = C * C / 4;
  int ntot = na4 + nb4 + nc4;
  cast3<<<(ntot + 255) / 256, 256, 0, stream>>>(x, na4, qkv_w, nb4, proj_w, nc4, xb, wqkv, wproj);

  dim3 g1(C3 / 128, N / 128);
  gemm_bt<0><<<g1, 256, 0, stream>>>(xb, wqkv, qkv_b, qbuf, kbuf, vbuf, nullptr, C, C3);

  flash_attn<<<768, 256, 0, stream>>>(qbuf, kbuf, vbuf, aob);

  dim3 g3(C / 128, N / 128);
  gemm_bt<1><<<g3, 256, 0, stream>>>(aob, wproj, proj_b, nullptr, nullptr, nullptr, out, C, C);
}